// Round 2
// baseline (163.626 us; speedup 1.0000x reference)
//
#include <hip/hip_runtime.h>

#define NV 64
#define NP 2016            // 64*63/2
#define NT 504             // NP/4 pair-groups per batch element
#define ALPHA_T (20.0f / 90.0f)

// ---------------- split path: kernel A — per-view factor table + out zero ----------------
__global__ __launch_bounds__(256) void gv_kernel(
    const float* __restrict__ views,   // (B, 64, 7)
    const float* __restrict__ s_gsd,
    const float* __restrict__ s_nrm,
    const float* __restrict__ s_dist,
    float* __restrict__ gvw,           // (B*64) out
    float* __restrict__ out,           // (B) zeroed here
    int B)
{
    const int tid = blockIdx.x * 256 + threadIdx.x;
    if (tid < B) out[tid] = 0.0f;
    const int n = B * NV;
    if (tid >= n) return;

    const float gsd_s = s_gsd[0], nrm_s = s_nrm[0], dist_s = s_dist[0];
    const float c_gsd  = 0.5f / (gsd_s * gsd_s);
    const float c_nrm  = 0.5f / (nrm_s * nrm_s);
    const float c_dist = 0.5f / (dist_s * dist_s);

    const float* vb = views + (size_t)tid * 7;
    float m  = (vb[0] == 1.0f) ? 1.0f : 0.0f;
    float x4 = vb[4], x5 = vb[5], x6 = vb[6];
    float x4sq = x4 * x4;
    gvw[tid] = m * __expf(-(x4sq * x4sq * c_gsd + x5 * x5 * c_nrm + x6 * x6 * c_dist));
}

// ---------------- split path: kernel B — pure pair stream, grid-stride ----------------
__global__ __launch_bounds__(256) void pair_kernel(
    const float* __restrict__ pairs,   // (B, 2016, 3) == flat float4[B*1512]
    const float* __restrict__ gvw,     // (B*64)
    const float* __restrict__ s_a1,
    const float* __restrict__ s_a2,
    const float* __restrict__ s_scale,
    float* __restrict__ out,           // (B), pre-zeroed
    int ntot)                          // B*NT total 4-pair tasks
{
    const int g    = blockIdx.x * 256 + threadIdx.x;
    const int S    = gridDim.x * 256;
    const int lane = threadIdx.x & 63;

    const float a1 = s_a1[0], a2 = s_a2[0], sc = s_scale[0];
    const float ia1     = 0.5f / (a1 * a1);
    const float ia2     = 0.5f / (a2 * a2);
    const float c_scale = 0.5f / (sc * sc);

    const float4* __restrict__ f4 = (const float4*)pairs;

    const int nit = (ntot + S - 1) / S;
    for (int it = 0; it < nit; ++it) {
        int task = g + it * S;
        const bool ok = task < ntot;
        const int tc = ok ? task : (ntot - 1);

        // task tc's 4 pairs live at byte offset 48*tc globally (contiguous across b)
        float4 q0 = f4[3 * tc + 0];
        float4 q1 = f4[3 * tc + 1];
        float4 q2 = f4[3 * tc + 2];

        int b = tc / NT;               // magic-mul division (constant divisor)
        int p = 4 * (tc - b * NT);

        // decode (i,j) for first pair of the group; sqrt amortized over 4 pairs
        int i = (int)((127.0f - sqrtf((float)(16129 - 8 * p))) * 0.5f);
        int Si = (i * (127 - i)) >> 1;
        if (Si > p) { --i; Si = (i * (127 - i)) >> 1; }
        else {
            int Si1 = ((i + 1) * (126 - i)) >> 1;
            if (Si1 <= p) { i = i + 1; Si = Si1; }
        }
        int j = i + 1 + (p - Si);

        const float pm[4] = {q0.x, q0.w, q1.z, q2.y};
        const float av[4] = {q0.y, q1.x, q1.w, q2.z};
        const float sv[4] = {q0.z, q1.y, q2.x, q2.w};

        const float* gvb = gvw + (b << 6);   // 256B window, L2/L3-hot
        float acc = 0.0f;
        #pragma unroll
        for (int u = 0; u < 4; ++u) {
            float a = av[u], s = sv[u];
            float coef = (a < ALPHA_T) ? ia1 : ia2;
            float base = __expf(-(a * a * coef + s * s * c_scale));
            if (a == ALPHA_T) base = 0.0f;   // sigma=0, expo=0 -> exp(-1/0)=0
            float v = base * gvb[i] * gvb[j];
            acc += (pm[u] != 0.0f) ? v : 0.0f;
            ++j;
            if (j >= NV) { ++i; j = i + 1; }
        }
        if (!ok) acc = 0.0f;

        // segmented reduce: consecutive lanes hold consecutive tasks, so b is
        // non-decreasing with <=2 distinct values per wave
        const int b0 = __shfl(b, 0, 64);
        float s0 = (b == b0) ? acc : 0.0f;
        float s1 = (b == b0) ? 0.0f : acc;
        #pragma unroll
        for (int off = 32; off > 0; off >>= 1) {
            s0 += __shfl_xor(s0, off, 64);
            s1 += __shfl_xor(s1, off, 64);
        }
        if (lane == 0 && s0 != 0.0f) atomicAdd(&out[b0], s0);
        if (lane == 63 && b != b0 && s1 != 0.0f) atomicAdd(&out[b], s1);
    }
}

// ---------------- fallback: known-good single kernel (if ws too small) ----------------
__global__ __launch_bounds__(256) void score_kernel(
    const float* __restrict__ views,
    const float* __restrict__ pairs,
    const float* __restrict__ s_a1,
    const float* __restrict__ s_a2,
    const float* __restrict__ s_gsd,
    const float* __restrict__ s_scale,
    const float* __restrict__ s_nrm,
    const float* __restrict__ s_dist,
    float* __restrict__ out)
{
    const int b = blockIdx.x;
    const int t = threadIdx.x;

    __shared__ float gv[NV];
    __shared__ float wsum[4];

    const float a1 = s_a1[0];
    const float a2 = s_a2[0];
    const float gsd_s   = s_gsd[0];
    const float scale_s = s_scale[0];
    const float nrm_s   = s_nrm[0];
    const float dist_s  = s_dist[0];

    const float ia1     = 0.5f / (a1 * a1);
    const float ia2     = 0.5f / (a2 * a2);
    const float c_gsd   = 0.5f / (gsd_s * gsd_s);
    const float c_scale = 0.5f / (scale_s * scale_s);
    const float c_nrm   = 0.5f / (nrm_s * nrm_s);
    const float c_dist  = 0.5f / (dist_s * dist_s);

    if (t < NV) {
        const float* vb = views + ((size_t)b * NV + t) * 7;
        float m  = (vb[0] == 1.0f) ? 1.0f : 0.0f;
        float x4 = vb[4], x5 = vb[5], x6 = vb[6];
        float x4sq = x4 * x4;
        float e = x4sq * x4sq * c_gsd + x5 * x5 * c_nrm + x6 * x6 * c_dist;
        gv[t] = m * __expf(-e);
    }
    __syncthreads();

    const float4* pb4 = (const float4*)(pairs + (size_t)b * NP * 3);
    float acc = 0.0f;

    for (int task = t; task < NT; task += 256) {
        float4 q0 = pb4[3 * task + 0];
        float4 q1 = pb4[3 * task + 1];
        float4 q2 = pb4[3 * task + 2];

        int p = 4 * task;
        int i = (int)((127.0f - sqrtf((float)(16129 - 8 * p))) * 0.5f);
        int Si = (i * (127 - i)) >> 1;
        if (Si > p) { --i; Si = (i * (127 - i)) >> 1; }
        else {
            int Si1 = ((i + 1) * (126 - i)) >> 1;
            if (Si1 <= p) { i = i + 1; Si = Si1; }
        }
        int j = i + 1 + (p - Si);

        const float pm[4] = {q0.x, q0.w, q1.z, q2.y};
        const float av[4] = {q0.y, q1.x, q1.w, q2.z};
        const float sv[4] = {q0.z, q1.y, q2.x, q2.w};

        #pragma unroll
        for (int u = 0; u < 4; ++u) {
            float a = av[u], s = sv[u];
            float coef = (a < ALPHA_T) ? ia1 : ia2;
            float base = __expf(-(a * a * coef + s * s * c_scale));
            if (a == ALPHA_T) base = 0.0f;
            float v = base * gv[i] * gv[j];
            acc += (pm[u] != 0.0f) ? v : 0.0f;
            ++j;
            if (j >= NV) { ++i; j = i + 1; }
        }
    }

    #pragma unroll
    for (int off = 32; off > 0; off >>= 1)
        acc += __shfl_down(acc, off, 64);

    const int wid  = t >> 6;
    const int lane = t & 63;
    if (lane == 0) wsum[wid] = acc;
    __syncthreads();
    if (t == 0) out[b] = wsum[0] + wsum[1] + wsum[2] + wsum[3];
}

extern "C" void kernel_launch(void* const* d_in, const int* in_sizes, int n_in,
                              void* d_out, int out_size, void* d_ws, size_t ws_size,
                              hipStream_t stream) {
    const float* views = (const float*)d_in[0];
    const float* pairs = (const float*)d_in[1];
    // d_in[2] = point_attribute (unused by the reference computation)
    const float* a1    = (const float*)d_in[3];
    const float* a2    = (const float*)d_in[4];
    const float* gsd   = (const float*)d_in[5];
    const float* scale = (const float*)d_in[6];
    const float* nrm   = (const float*)d_in[7];
    const float* dist  = (const float*)d_in[8];
    float* out = (float*)d_out;

    const int B = in_sizes[0] / (NV * 7);

    if (d_ws != nullptr && ws_size >= (size_t)B * NV * sizeof(float)) {
        float* gvw = (float*)d_ws;
        const int nviews = B * NV;
        gv_kernel<<<(nviews + 255) / 256, 256, 0, stream>>>(views, gsd, nrm, dist, gvw, out, B);
        const int ntot = B * NT;
        pair_kernel<<<2048, 256, 0, stream>>>(pairs, gvw, a1, a2, scale, out, ntot);
    } else {
        score_kernel<<<B, 256, 0, stream>>>(views, pairs, a1, a2, gsd, scale, nrm, dist, out);
    }
}